// Round 5
// baseline (208.011 us; speedup 1.0000x reference)
//
#include <hip/hip_runtime.h>

typedef __bf16 bf16x8 __attribute__((ext_vector_type(8)));
typedef float f32x16 __attribute__((ext_vector_type(16)));
typedef short short8 __attribute__((ext_vector_type(8)));

#define S 512
#define CH 16

#define ELT(v, c) ((c)==0 ? (v).x : (c)==1 ? (v).y : (c)==2 ? (v).z : (v).w)

__device__ __forceinline__ float swishf(float z) {
    return z * __builtin_amdgcn_rcpf(1.0f + __expf(-z));
}

// All GEMMs transposed: D = W^T * data (weights = A-operand).
// 32x32x16 maps (R2-R4 verified): A[row=l&31][k=(l>>5)*8+j], B[k=(l>>5)*8+j][col=l&31],
// D reg r: [row=(r&3)+8*(r>>2)+4*(l>>5)][col=l&31].
// GEMM1 fused perceive+W1: K=144, 9 steps; k-slot(s,hi,j): s=dr*3+dc, channel c=hi*8+j.
// GEMM2 (K=64): k-slot(t,hi,j) -> h1-feat (t>>1)*32 + 4*hi + (t&1)*16 + (j&3)+8*(j>>2)
// GEMM3 (K=32): k-slot(t,hi,j) -> h2-feat 4*hi + t*16 + (j&3)+8*(j>>2)
//   W3 output columns PERMUTED: D-row m holds channel ch(m)= (m&3) | ((m>>3)&1)<<2 | ((m>>2)&1)<<3
//   so lane hi's regs r=0..7 are channels 8*hi+0..7 (contiguous float4 x2 epilogue).
// ws shorts [0,12288): fi=0..17 GEMM1 (fi=n*9+s), 18..21 GEMM2, 22..23 GEMM3.
// byte 24576: f32 biases b1[64] b2[32] b3[16].
__global__ void prep_weights(const float* __restrict__ W1, const float* __restrict__ b1,
                             const float* __restrict__ W2, const float* __restrict__ b2,
                             const float* __restrict__ W3, const float* __restrict__ b3,
                             short* __restrict__ wsf, float* __restrict__ wsb)
{
    int idx = blockIdx.x * 256 + threadIdx.x;
    if (idx < 12288) {
        int fi = idx >> 9, rem = idx & 511;
        int lane = rem >> 3, j = rem & 7;
        int col = lane & 31, hi = lane >> 5;
        int jp = (j & 3) + 8 * (j >> 2);
        float v;
        if (fi < 18) {
            int n = fi / 9, s = fi - n * 9;
            int dr = s / 3, dc = s - dr * 3;
            int c = hi * 8 + j;
            const float wgt0 = (dr == 1) ? 2.f : 1.f;
            const float wgt1 = (dc == 1) ? 2.f : 1.f;
            const float dlt0 = (float)(dr - 1);
            const float dlt1 = (float)(dc - 1);
            const float lapm[9] = {0.25f, 0.5f, 0.25f, 0.5f, -3.f, 0.5f, 0.25f, 0.5f, 0.25f};
            float kI  = (s == 4) ? 1.f : 0.f;
            float kdx = wgt0 * dlt1 * 0.125f;
            float kdy = dlt0 * wgt1 * 0.125f;
            float klp = lapm[s];
            float kav = 1.f / 9.f;
            const float* wr = W1 + (c * 5) * 64 + n * 32 + col;
            v = kI * wr[0] + kdx * wr[64] + kdy * wr[128] + klp * wr[192] + kav * wr[256];
        } else if (fi < 22) {
            int t = fi - 18;
            int rowW = (t >> 1) * 32 + 4 * hi + (t & 1) * 16 + jp;
            v = W2[rowW * 32 + col];
        } else {
            int t = fi - 22;
            int rowW = 4 * hi + t * 16 + jp;               // h2-feature (K index)
            int ch = (col & 3) | (((col >> 3) & 1) << 2) | (((col >> 2) & 1) << 3);
            v = (col < 16) ? W3[rowW * 16 + ch] : 0.0f;    // permuted out-ch, pad M 16->32
        }
        __bf16 b = (__bf16)v;
        wsf[idx] = __builtin_bit_cast(short, b);
    }
    if (blockIdx.x == 0) {
        int t = threadIdx.x;
        if (t < 64) wsb[t] = b1[t];
        else if (t < 96) wsb[t] = b2[t - 64];
        else if (t < 112) wsb[t] = b3[t - 96];
    }
}

// load one x-row's 3x(2 float4) neighborhood for lane (col,hi); clamped+zeroed OOB
__device__ __forceinline__ void loadrow(const float* __restrict__ xb, int gr, int px0,
                                        int col, int hi, bool edgeStrip, float4 L[3][2])
{
    const bool rv = (unsigned)gr < (unsigned)S;
    const int grc = rv ? gr : (gr < 0 ? 0 : S - 1);
    if (!edgeStrip) {
        const float* rp = xb + ((size_t)grc * S + (px0 + col - 1)) * CH + hi * 8;
#pragma unroll
        for (int dc = 0; dc < 3; ++dc) {
            L[dc][0] = *reinterpret_cast<const float4*>(rp + dc * CH);
            L[dc][1] = *reinterpret_cast<const float4*>(rp + dc * CH + 4);
        }
    } else {
#pragma unroll
        for (int dc = 0; dc < 3; ++dc) {
            int c = px0 + col - 1 + dc;
            bool ok = (unsigned)c < (unsigned)S;
            int cl = min(max(c, 0), S - 1);
            const float* p = xb + ((size_t)grc * S + cl) * CH + hi * 8;
            float4 v0 = *reinterpret_cast<const float4*>(p);
            float4 v1 = *reinterpret_cast<const float4*>(p + 4);
            if (!ok) { v0 = make_float4(0.f, 0.f, 0.f, 0.f); v1 = v0; }
            L[dc][0] = v0; L[dc][1] = v1;
        }
    }
    if (!rv) {
#pragma unroll
        for (int dc = 0; dc < 3; ++dc) {
            L[dc][0] = make_float4(0.f, 0.f, 0.f, 0.f);
            L[dc][1] = L[dc][0];
        }
    }
}

__device__ __forceinline__ short8 cvt2(float4 a, float4 b) {
    short8 f;
    f[0] = __builtin_bit_cast(short, (__bf16)a.x);
    f[1] = __builtin_bit_cast(short, (__bf16)a.y);
    f[2] = __builtin_bit_cast(short, (__bf16)a.z);
    f[3] = __builtin_bit_cast(short, (__bf16)a.w);
    f[4] = __builtin_bit_cast(short, (__bf16)b.x);
    f[5] = __builtin_bit_cast(short, (__bf16)b.y);
    f[6] = __builtin_bit_cast(short, (__bf16)b.z);
    f[7] = __builtin_bit_cast(short, (__bf16)b.w);
    return f;
}

#define NR 8

__global__ __launch_bounds__(256, 3) void nca_fused(
    const float* __restrict__ x, const float* __restrict__ noise,
    const short* __restrict__ wsf, const float* __restrict__ wsb,
    float* __restrict__ out)
{
    __shared__ short wlds[12288];
    {
        const int4* src = reinterpret_cast<const int4*>(wsf);
        int4* dst = reinterpret_cast<int4*>(wlds);
        for (int i = threadIdx.x; i < 1536; i += 256) dst[i] = src[i];
    }
    __syncthreads();                                    // the only barrier

    const int tid = threadIdx.x, bid = blockIdx.x;
    const int wv = tid >> 6, lane = tid & 63;
    const int col = lane & 31, hi = lane >> 5;
    const int st = bid & 15;                            // 16 strips of 32 px
    const int rgp = (bid >> 4) & 15;                    // 16 groups of 32 rows
    const int bb = bid >> 8;                            // batch
    const int px0 = st * 32;
    const int r0 = (rgp * 4 + wv) * NR;                 // this wave's first output row
    const bool edgeStrip = (px0 == 0) || (px0 == 480);
    const float* xb = x + (size_t)bb * S * S * CH;
    const short8* wf = reinterpret_cast<const short8*>(wlds);

    // per-lane bias vectors (from LDS-adjacent global; tiny, L1-hot)
    float4 bA = *reinterpret_cast<const float4*>(wsb + 96 + 8 * hi);
    float4 bB = *reinterpret_cast<const float4*>(wsb + 96 + 8 * hi + 4);

    // ---- prologue: rows r0-1, r0, r0+1 -> frag rows 0,1,2 ----
    short8 fr[3][3];
    {
        float4 P[3][2];
        loadrow(xb, r0 - 1, px0, col, hi, edgeStrip, P);
#pragma unroll
        for (int dc = 0; dc < 3; ++dc) fr[0][dc] = cvt2(P[dc][0], P[dc][1]);
        loadrow(xb, r0, px0, col, hi, edgeStrip, P);
#pragma unroll
        for (int dc = 0; dc < 3; ++dc) fr[1][dc] = cvt2(P[dc][0], P[dc][1]);
        loadrow(xb, r0 + 1, px0, col, hi, edgeStrip, P);
#pragma unroll
        for (int dc = 0; dc < 3; ++dc) fr[2][dc] = cvt2(P[dc][0], P[dc][1]);
    }

#pragma unroll
    for (int i = 0; i < NR; ++i) {
        const int r = r0 + i;

        // 1. prefetch x row r+2 (consumed at step 6, a full pipeline later)
        float4 NL[3][2];
        loadrow(xb, r + 2, px0, col, hi, edgeStrip, NL);

        // 2. early-issue center x + noise for this row's epilogue
        const float* cp = xb + ((size_t)r * S + px0 + col) * CH + 8 * hi;
        float4 c0 = *reinterpret_cast<const float4*>(cp);
        float4 c1 = *reinterpret_cast<const float4*>(cp + 4);
        float nz = noise[((size_t)(bb * S + r)) * S + px0 + col];

        // 3. GEMM1 (fused perceive+W1): interleave n=0/1 accs to hide MFMA latency
        f32x16 acc1[2] = {{}, {}};
#pragma unroll
        for (int dr = 0; dr < 3; ++dr)
#pragma unroll
            for (int dc = 0; dc < 3; ++dc) {
                const int s = dr * 3 + dc;
                bf16x8 bfrag = __builtin_bit_cast(bf16x8, fr[(i + dr) % 3][dc]);
                bf16x8 a0 = __builtin_bit_cast(bf16x8, wf[s * 64 + lane]);
                bf16x8 a1 = __builtin_bit_cast(bf16x8, wf[(9 + s) * 64 + lane]);
                acc1[0] = __builtin_amdgcn_mfma_f32_32x32x16_bf16(a0, bfrag, acc1[0], 0, 0, 0);
                acc1[1] = __builtin_amdgcn_mfma_f32_32x32x16_bf16(a1, bfrag, acc1[1], 0, 0, 0);
            }

        // 4a. swish + bias -> B2 frags
        short8 b2f[4];
#pragma unroll
        for (int t = 0; t < 4; ++t) {
            int n = t >> 1;
            float4 bq0 = *reinterpret_cast<const float4*>(wsb + n * 32 + 4 * hi + 16 * (t & 1));
            float4 bq1 = *reinterpret_cast<const float4*>(wsb + n * 32 + 4 * hi + 16 * (t & 1) + 8);
#pragma unroll
            for (int j = 0; j < 8; ++j) {
                float bias = (j < 4) ? ELT(bq0, j & 3) : ELT(bq1, j & 3);
                float h = swishf(acc1[n][(t & 1) * 8 + j] + bias);
                b2f[t][j] = __builtin_bit_cast(short, (__bf16)h);
            }
        }

        // 4b. GEMM2
        f32x16 acc2 = {};
#pragma unroll
        for (int t = 0; t < 4; ++t) {
            bf16x8 a = __builtin_bit_cast(bf16x8, wf[(18 + t) * 64 + lane]);
            acc2 = __builtin_amdgcn_mfma_f32_32x32x16_bf16(a, __builtin_bit_cast(bf16x8, b2f[t]), acc2, 0, 0, 0);
        }

        // 4c. swish + bias -> B3 frags
        short8 b3f[2];
#pragma unroll
        for (int t = 0; t < 2; ++t) {
            float4 cq0 = *reinterpret_cast<const float4*>(wsb + 64 + 4 * hi + 16 * t);
            float4 cq1 = *reinterpret_cast<const float4*>(wsb + 64 + 4 * hi + 16 * t + 8);
#pragma unroll
            for (int j = 0; j < 8; ++j) {
                float bias = (j < 4) ? ELT(cq0, j & 3) : ELT(cq1, j & 3);
                float h = swishf(acc2[t * 8 + j] + bias);
                b3f[t][j] = __builtin_bit_cast(short, (__bf16)h);
            }
        }

        // 4d. GEMM3 (W3 out-permuted: reg r -> ch 8*hi + (r&3)+4*(r>>2))
        f32x16 acc3 = {};
#pragma unroll
        for (int t = 0; t < 2; ++t) {
            bf16x8 a = __builtin_bit_cast(bf16x8, wf[(22 + t) * 64 + lane]);
            acc3 = __builtin_amdgcn_mfma_f32_32x32x16_bf16(a, __builtin_bit_cast(bf16x8, b3f[t]), acc3, 0, 0, 0);
        }

        // 5. epilogue: masked residual, contiguous float4 x2 per lane
        {
            size_t pix = ((size_t)(bb * S + r)) * S + px0 + col;
            float msk = (nz <= 0.5f) ? 1.f : 0.f;
            float4 o0, o1;
            o0.x = c0.x + (acc3[0] + bA.x) * msk;
            o0.y = c0.y + (acc3[1] + bA.y) * msk;
            o0.z = c0.z + (acc3[2] + bA.z) * msk;
            o0.w = c0.w + (acc3[3] + bA.w) * msk;
            o1.x = c1.x + (acc3[4] + bB.x) * msk;
            o1.y = c1.y + (acc3[5] + bB.y) * msk;
            o1.z = c1.z + (acc3[6] + bB.z) * msk;
            o1.w = c1.w + (acc3[7] + bB.w) * msk;
            float* op = out + pix * CH + 8 * hi;
            *reinterpret_cast<float4*>(op) = o0;
            *reinterpret_cast<float4*>(op + 4) = o1;
        }

        // 6. retire prefetched row r+2 into frag slot (overwrites row r-1)
#pragma unroll
        for (int dc = 0; dc < 3; ++dc)
            fr[i % 3][dc] = cvt2(NL[dc][0], NL[dc][1]);
    }
}

extern "C" void kernel_launch(void* const* d_in, const int* in_sizes, int n_in,
                              void* d_out, int out_size, void* d_ws, size_t ws_size,
                              hipStream_t stream)
{
    const float* x     = (const float*)d_in[0];
    const float* noise = (const float*)d_in[1];
    const float* W1    = (const float*)d_in[2];
    const float* b1    = (const float*)d_in[3];
    const float* W2    = (const float*)d_in[4];
    const float* b2    = (const float*)d_in[5];
    const float* W3    = (const float*)d_in[6];
    const float* b3    = (const float*)d_in[7];
    short* wsf = (short*)d_ws;
    float* wsb = (float*)((char*)d_ws + 24576);
    float* out = (float*)d_out;

    hipLaunchKernelGGL(prep_weights, dim3(48), dim3(256), 0, stream,
                       W1, b1, W2, b2, W3, b3, wsf, wsb);
    hipLaunchKernelGGL(nca_fused, dim3(4 * 16 * 16), dim3(256), 0, stream,
                       x, noise, wsf, wsb, out);
}

// Round 9
// 206.035 us; speedup vs baseline: 1.0096x; 1.0096x over previous
//
#include <hip/hip_runtime.h>

typedef __bf16 bf16x8 __attribute__((ext_vector_type(8)));
typedef float f32x4 __attribute__((ext_vector_type(4)));
typedef float f32x16 __attribute__((ext_vector_type(16)));
typedef short short8 __attribute__((ext_vector_type(8)));

#define S 512
#define CH 16

#define ELT(v, c) ((c)==0 ? (v).x : (c)==1 ? (v).y : (c)==2 ? (v).z : (v).w)

__device__ __forceinline__ float swishf(float z) {
    return z * __builtin_amdgcn_rcpf(1.0f + __expf(-z));
}

// All GEMMs transposed: D = W^T * data (weights = A-operand).
// 32x32x16 maps (R2-R5 verified): A[row=l&31][k=(l>>5)*8+j], B[k=(l>>5)*8+j][col=l&31],
// D reg r: [row=(r&3)+8*(r>>2)+4*(l>>5)][col=l&31].
// GEMM1 fused perceive+W1: K=144, 9 steps; k-slot(s,hi,j): s=dr*3+dc, channel c=hi*8+j.
// GEMM2 (K=64): k-slot(t,hi,j) -> h1-feat (t>>1)*32 + 4*hi + (t&1)*16 + (j&3)+8*(j>>2)
// GEMM3 (K=32): k-slot(t,hi,j) -> h2-feat 4*hi + t*16 + (j&3)+8*(j>>2)
//   W3 output columns PERMUTED so lane hi's regs r=0..7 are channels 8*hi+0..7.
// ws shorts [0,12288): fi=0..17 GEMM1 (fi=n*9+s), 18..21 GEMM2, 22..23 GEMM3.
// byte 24576: f32 biases b1[64] b2[32] b3[16].
__global__ void prep_weights(const float* __restrict__ W1, const float* __restrict__ b1,
                             const float* __restrict__ W2, const float* __restrict__ b2,
                             const float* __restrict__ W3, const float* __restrict__ b3,
                             short* __restrict__ wsf, float* __restrict__ wsb)
{
    int idx = blockIdx.x * 256 + threadIdx.x;
    if (idx < 12288) {
        int fi = idx >> 9, rem = idx & 511;
        int lane = rem >> 3, j = rem & 7;
        int col = lane & 31, hi = lane >> 5;
        int jp = (j & 3) + 8 * (j >> 2);
        float v;
        if (fi < 18) {
            int n = fi / 9, s = fi - n * 9;
            int dr = s / 3, dc = s - dr * 3;
            int c = hi * 8 + j;
            const float wgt0 = (dr == 1) ? 2.f : 1.f;
            const float wgt1 = (dc == 1) ? 2.f : 1.f;
            const float dlt0 = (float)(dr - 1);
            const float dlt1 = (float)(dc - 1);
            const float lapm[9] = {0.25f, 0.5f, 0.25f, 0.5f, -3.f, 0.5f, 0.25f, 0.5f, 0.25f};
            float kI  = (s == 4) ? 1.f : 0.f;
            float kdx = wgt0 * dlt1 * 0.125f;
            float kdy = dlt0 * wgt1 * 0.125f;
            float klp = lapm[s];
            float kav = 1.f / 9.f;
            const float* wr = W1 + (c * 5) * 64 + n * 32 + col;
            v = kI * wr[0] + kdx * wr[64] + kdy * wr[128] + klp * wr[192] + kav * wr[256];
        } else if (fi < 22) {
            int t = fi - 18;
            int rowW = (t >> 1) * 32 + 4 * hi + (t & 1) * 16 + jp;
            v = W2[rowW * 32 + col];
        } else {
            int t = fi - 22;
            int rowW = 4 * hi + t * 16 + jp;               // h2-feature (K index)
            int ch = (col & 3) | (((col >> 3) & 1) << 2) | (((col >> 2) & 1) << 3);
            v = (col < 16) ? W3[rowW * 16 + ch] : 0.0f;    // permuted out-ch, pad M 16->32
        }
        __bf16 b = (__bf16)v;
        wsf[idx] = __builtin_bit_cast(short, b);
    }
    if (blockIdx.x == 0) {
        int t = threadIdx.x;
        if (t < 64) wsb[t] = b1[t];
        else if (t < 96) wsb[t] = b2[t - 64];
        else if (t < 112) wsb[t] = b3[t - 96];
    }
}

// load one x-row's 3x(2 float4) neighborhood for lane (col,hi); clamped+zeroed OOB
__device__ __forceinline__ void loadrow(const float* __restrict__ xb, int gr, int px0,
                                        int col, int hi, bool edgeStrip, float4 L[3][2])
{
    const bool rv = (unsigned)gr < (unsigned)S;
    const int grc = rv ? gr : (gr < 0 ? 0 : S - 1);
    if (!edgeStrip) {
        const float* rp = xb + ((size_t)grc * S + (px0 + col - 1)) * CH + hi * 8;
#pragma unroll
        for (int dc = 0; dc < 3; ++dc) {
            L[dc][0] = *reinterpret_cast<const float4*>(rp + dc * CH);
            L[dc][1] = *reinterpret_cast<const float4*>(rp + dc * CH + 4);
        }
    } else {
#pragma unroll
        for (int dc = 0; dc < 3; ++dc) {
            int c = px0 + col - 1 + dc;
            bool ok = (unsigned)c < (unsigned)S;
            int cl = min(max(c, 0), S - 1);
            const float* p = xb + ((size_t)grc * S + cl) * CH + hi * 8;
            float4 v0 = *reinterpret_cast<const float4*>(p);
            float4 v1 = *reinterpret_cast<const float4*>(p + 4);
            if (!ok) { v0 = make_float4(0.f, 0.f, 0.f, 0.f); v1 = v0; }
            L[dc][0] = v0; L[dc][1] = v1;
        }
    }
    if (!rv) {
#pragma unroll
        for (int dc = 0; dc < 3; ++dc) {
            L[dc][0] = make_float4(0.f, 0.f, 0.f, 0.f);
            L[dc][1] = L[dc][0];
        }
    }
}

__device__ __forceinline__ short8 cvt2(float4 a, float4 b) {
    short8 f;
    f[0] = __builtin_bit_cast(short, (__bf16)a.x);
    f[1] = __builtin_bit_cast(short, (__bf16)a.y);
    f[2] = __builtin_bit_cast(short, (__bf16)a.z);
    f[3] = __builtin_bit_cast(short, (__bf16)a.w);
    f[4] = __builtin_bit_cast(short, (__bf16)b.x);
    f[5] = __builtin_bit_cast(short, (__bf16)b.y);
    f[6] = __builtin_bit_cast(short, (__bf16)b.z);
    f[7] = __builtin_bit_cast(short, (__bf16)b.w);
    return f;
}

#define NR 4

__global__ __launch_bounds__(256, 4) void nca_fused(
    const float* __restrict__ x, const float* __restrict__ noise,
    const short* __restrict__ wsf, const float* __restrict__ wsb,
    float* __restrict__ out)
{
    __shared__ short wlds[12288];
    {
        const int4* src = reinterpret_cast<const int4*>(wsf);
        int4* dst = reinterpret_cast<int4*>(wlds);
        for (int i = threadIdx.x; i < 1536; i += 256) dst[i] = src[i];
    }
    __syncthreads();                                    // the only barrier

    const int tid = threadIdx.x, bid = blockIdx.x;
    const int wv = tid >> 6, lane = tid & 63;
    const int col = lane & 31, hi = lane >> 5;

    // XCD-aware decode (bijective on 2048 = 8 xcd * 256):
    // XCD x owns 4 contiguous rowgroups of one (strip,batch) -> halo rows L2-local.
    const int xcd = bid & 7;
    const int k = bid >> 3;
    const int rg = xcd * 4 + (k & 3);                   // rowgroup 0..31 (16 rows each)
    const int sb = k >> 2;                              // 0..63
    const int st = sb & 15;                             // strip
    const int bb = sb >> 4;                             // batch
    const int px0 = st * 32;
    const int r0 = rg * 16 + wv * NR;                   // this wave's first output row
    const bool edgeStrip = (px0 == 0) || (px0 == 480);
    const float* xb = x + (size_t)bb * S * S * CH;
    const short8* wf = reinterpret_cast<const short8*>(wlds);

    float4 bA = *reinterpret_cast<const float4*>(wsb + 96 + 8 * hi);
    float4 bB = *reinterpret_cast<const float4*>(wsb + 96 + 8 * hi + 4);

    // ---- prologue: rows r0-1, r0, r0+1 -> frag rows 0,1,2 ----
    short8 fr[3][3];
    {
        float4 P[3][2];
        loadrow(xb, r0 - 1, px0, col, hi, edgeStrip, P);
#pragma unroll
        for (int dc = 0; dc < 3; ++dc) fr[0][dc] = cvt2(P[dc][0], P[dc][1]);
        loadrow(xb, r0, px0, col, hi, edgeStrip, P);
#pragma unroll
        for (int dc = 0; dc < 3; ++dc) fr[1][dc] = cvt2(P[dc][0], P[dc][1]);
        loadrow(xb, r0 + 1, px0, col, hi, edgeStrip, P);
#pragma unroll
        for (int dc = 0; dc < 3; ++dc) fr[2][dc] = cvt2(P[dc][0], P[dc][1]);
    }

#pragma unroll
    for (int i = 0; i < NR; ++i) {
        const int r = r0 + i;

        // 1. prefetch x row r+2 (consumed at the end of this iteration, for iter i+1)
        float4 NL[3][2];
        if (i + 1 < NR) loadrow(xb, r + 2, px0, col, hi, edgeStrip, NL);

        // 2. early-issue center x + noise for this row's epilogue
        const float* cp = xb + ((size_t)r * S + px0 + col) * CH + 8 * hi;
        float4 c0 = *reinterpret_cast<const float4*>(cp);
        float4 c1 = *reinterpret_cast<const float4*>(cp + 4);
        float nz = noise[((size_t)(bb * S + r)) * S + px0 + col];

        // 3. GEMM1 (fused perceive+W1): two accs interleaved
        f32x16 acc1[2] = {{}, {}};
#pragma unroll
        for (int dr = 0; dr < 3; ++dr)
#pragma unroll
            for (int dc = 0; dc < 3; ++dc) {
                const int s = dr * 3 + dc;
                bf16x8 bfrag = __builtin_bit_cast(bf16x8, fr[(i + dr) % 3][dc]);
                bf16x8 a0 = __builtin_bit_cast(bf16x8, wf[s * 64 + lane]);
                bf16x8 a1 = __builtin_bit_cast(bf16x8, wf[(9 + s) * 64 + lane]);
                acc1[0] = __builtin_amdgcn_mfma_f32_32x32x16_bf16(a0, bfrag, acc1[0], 0, 0, 0);
                acc1[1] = __builtin_amdgcn_mfma_f32_32x32x16_bf16(a1, bfrag, acc1[1], 0, 0, 0);
            }

        // 4a. swish + bias -> B2 frags
        short8 b2f[4];
#pragma unroll
        for (int t = 0; t < 4; ++t) {
            int n = t >> 1;
            float4 bq0 = *reinterpret_cast<const float4*>(wsb + n * 32 + 4 * hi + 16 * (t & 1));
            float4 bq1 = *reinterpret_cast<const float4*>(wsb + n * 32 + 4 * hi + 16 * (t & 1) + 8);
#pragma unroll
            for (int j = 0; j < 8; ++j) {
                float bias = (j < 4) ? ELT(bq0, j & 3) : ELT(bq1, j & 3);
                float h = swishf(acc1[n][(t & 1) * 8 + j] + bias);
                b2f[t][j] = __builtin_bit_cast(short, (__bf16)h);
            }
        }

        // 4b. GEMM2
        f32x16 acc2 = {};
#pragma unroll
        for (int t = 0; t < 4; ++t) {
            bf16x8 a = __builtin_bit_cast(bf16x8, wf[(18 + t) * 64 + lane]);
            acc2 = __builtin_amdgcn_mfma_f32_32x32x16_bf16(a, __builtin_bit_cast(bf16x8, b2f[t]), acc2, 0, 0, 0);
        }

        // 4c. swish + bias -> B3 frags
        short8 b3f[2];
#pragma unroll
        for (int t = 0; t < 2; ++t) {
            float4 cq0 = *reinterpret_cast<const float4*>(wsb + 64 + 4 * hi + 16 * t);
            float4 cq1 = *reinterpret_cast<const float4*>(wsb + 64 + 4 * hi + 16 * t + 8);
#pragma unroll
            for (int j = 0; j < 8; ++j) {
                float bias = (j < 4) ? ELT(cq0, j & 3) : ELT(cq1, j & 3);
                float h = swishf(acc2[t * 8 + j] + bias);
                b3f[t][j] = __builtin_bit_cast(short, (__bf16)h);
            }
        }

        // 4d. GEMM3 (W3 out-permuted: reg r -> ch 8*hi + (r&3)+4*(r>>2))
        f32x16 acc3 = {};
#pragma unroll
        for (int t = 0; t < 2; ++t) {
            bf16x8 a = __builtin_bit_cast(bf16x8, wf[(22 + t) * 64 + lane]);
            acc3 = __builtin_amdgcn_mfma_f32_32x32x16_bf16(a, __builtin_bit_cast(bf16x8, b3f[t]), acc3, 0, 0, 0);
        }

        // 5. epilogue: masked residual, nontemporal f32x4 x2 per lane
        {
            size_t pix = ((size_t)(bb * S + r)) * S + px0 + col;
            float msk = (nz <= 0.5f) ? 1.f : 0.f;
            f32x4 o0, o1;
            o0[0] = c0.x + (acc3[0] + bA.x) * msk;
            o0[1] = c0.y + (acc3[1] + bA.y) * msk;
            o0[2] = c0.z + (acc3[2] + bA.z) * msk;
            o0[3] = c0.w + (acc3[3] + bA.w) * msk;
            o1[0] = c1.x + (acc3[4] + bB.x) * msk;
            o1[1] = c1.y + (acc3[5] + bB.y) * msk;
            o1[2] = c1.z + (acc3[6] + bB.z) * msk;
            o1[3] = c1.w + (acc3[7] + bB.w) * msk;
            float* op = out + pix * CH + 8 * hi;
            __builtin_nontemporal_store(o0, reinterpret_cast<f32x4*>(op));
            __builtin_nontemporal_store(o1, reinterpret_cast<f32x4*>(op + 4));
        }

        // 6. retire prefetched row r+2 into frag slot (overwrites row r-1)
        if (i + 1 < NR) {
#pragma unroll
            for (int dc = 0; dc < 3; ++dc)
                fr[i % 3][dc] = cvt2(NL[dc][0], NL[dc][1]);
        }
    }
}

extern "C" void kernel_launch(void* const* d_in, const int* in_sizes, int n_in,
                              void* d_out, int out_size, void* d_ws, size_t ws_size,
                              hipStream_t stream)
{
    const float* x     = (const float*)d_in[0];
    const float* noise = (const float*)d_in[1];
    const float* W1    = (const float*)d_in[2];
    const float* b1    = (const float*)d_in[3];
    const float* W2    = (const float*)d_in[4];
    const float* b2    = (const float*)d_in[5];
    const float* W3    = (const float*)d_in[6];
    const float* b3    = (const float*)d_in[7];
    short* wsf = (short*)d_ws;
    float* wsb = (float*)((char*)d_ws + 24576);
    float* out = (float*)d_out;

    hipLaunchKernelGGL(prep_weights, dim3(48), dim3(256), 0, stream,
                       W1, b1, W2, b2, W3, b3, wsf, wsb);
    hipLaunchKernelGGL(nca_fused, dim3(2048), dim3(256), 0, stream,
                       x, noise, wsf, wsb, out);
}